// Round 1
// baseline (2938.588 us; speedup 1.0000x reference)
//
#include <hip/hip_runtime.h>
#include <math.h>

// Problem constants (match reference)
#define NU_ 500000
#define NI_ 200000
#define NN_ 700000            // NU + NI
#define D_  64
#define E_  2000000
#define B_  131072

// ---------------------------------------------------------------------------
// Degree histogram: deg[v] += 1 for both endpoints of every edge.
// Counts are exact in fp32 (deg << 2^24).
__global__ __launch_bounds__(256) void deg_kernel(const int* __restrict__ eu,
                                                  const int* __restrict__ ei,
                                                  float* __restrict__ degf) {
    int e = blockIdx.x * 256 + threadIdx.x;
    if (e >= E_) return;
    unsafeAtomicAdd(&degf[eu[e]], 1.0f);
    unsafeAtomicAdd(&degf[NU_ + ei[e]], 1.0f);
}

// In-place: degf[v] -> (deg>0 ? 1/sqrt(deg) : 0)
__global__ __launch_bounds__(256) void inv_kernel(float* __restrict__ degf) {
    int v = blockIdx.x * 256 + threadIdx.x;
    if (v >= NN_) return;
    float d = degf[v];
    degf[v] = (d > 0.0f) ? (1.0f / sqrtf(d)) : 0.0f;
}

// ---------------------------------------------------------------------------
// One wave (64 lanes) per edge, lane d handles feature d.
// srcX indexed by user-node id (su*64+d); dstX indexed by item-node id
// (sv*64+d) where sv = ei+NU  (for layer 0, dstX = item_emb - NU*64).
__global__ __launch_bounds__(256) void prop_kernel(const float* __restrict__ srcX,
                                                   const float* __restrict__ dstX,
                                                   const int* __restrict__ eu,
                                                   const int* __restrict__ ei,
                                                   const float* __restrict__ inv,
                                                   float* __restrict__ out) {
    int t = blockIdx.x * 256 + threadIdx.x;
    int e = t >> 6;           // wave-uniform edge id
    int d = t & 63;
    int su = eu[e];
    int sv = ei[e] + NU_;
    float w  = inv[su] * inv[sv];
    float xs = srcX[(size_t)su * D_ + d];
    float xd = dstX[(size_t)sv * D_ + d];
    unsafeAtomicAdd(&out[(size_t)sv * D_ + d], xs * w);
    unsafeAtomicAdd(&out[(size_t)su * D_ + d], xd * w);
}

// ---------------------------------------------------------------------------
// Z accumulators over the gathered rows only.
// t covers 2*B waves: first B -> Zu (users), next B -> Zi (items).
__global__ __launch_bounds__(256) void zinit_kernel(const float* __restrict__ ue,
                                                    const float* __restrict__ ie,
                                                    const int* __restrict__ users,
                                                    const int* __restrict__ items,
                                                    float* __restrict__ Zu,
                                                    float* __restrict__ Zi) {
    int t = blockIdx.x * 256 + threadIdx.x;
    int b = t >> 6;
    int d = t & 63;
    if (b < B_) {
        Zu[(size_t)b * D_ + d] = ue[(size_t)users[b] * D_ + d];
    } else {
        int bb = b - B_;
        Zi[(size_t)bb * D_ + d] = ie[(size_t)items[bb] * D_ + d];
    }
}

__global__ __launch_bounds__(256) void zacc_kernel(const float* __restrict__ x,
                                                   const int* __restrict__ users,
                                                   const int* __restrict__ items,
                                                   float* __restrict__ Zu,
                                                   float* __restrict__ Zi) {
    int t = blockIdx.x * 256 + threadIdx.x;
    int b = t >> 6;
    int d = t & 63;
    if (b < B_) {
        Zu[(size_t)b * D_ + d] += x[(size_t)users[b] * D_ + d];
    } else {
        int bb = b - B_;
        Zi[(size_t)bb * D_ + d] += x[((size_t)items[bb] + NU_) * D_ + d];
    }
}

// ---------------------------------------------------------------------------
// One wave per pair b. Lane l: f = l>>4, d = l&15.
// scores[b] = (1/16) * sum_{f,g} fw[f,g] * dot(Zu[b, f*16:..], Zi[b, g*16:..])
__global__ __launch_bounds__(256) void score_kernel(const float* __restrict__ Zu,
                                                    const float* __restrict__ Zi,
                                                    const float* __restrict__ fw,
                                                    float* __restrict__ out) {
    int t = blockIdx.x * 256 + threadIdx.x;
    int b = t >> 6;
    int l = t & 63;
    int f = l >> 4;
    int dd = l & 15;
    float pu = Zu[(size_t)b * D_ + l];
    float s = 0.0f;
#pragma unroll
    for (int g = 0; g < 4; ++g) {
        float pi = Zi[(size_t)b * D_ + g * 16 + dd];
        float p = pu * pi;
        // sum over the 16 lanes of this f-group (lanes share bits 4..5)
        p += __shfl_xor(p, 1);
        p += __shfl_xor(p, 2);
        p += __shfl_xor(p, 4);
        p += __shfl_xor(p, 8);
        s += fw[f * 4 + g] * p;
    }
    // combine the 4 f-groups
    s += __shfl_xor(s, 16);
    s += __shfl_xor(s, 32);
    if (l == 0) out[b] = s * 0.0625f;  // (1/4)*(1/4) layer-mean scaling
}

// ---------------------------------------------------------------------------
extern "C" void kernel_launch(void* const* d_in, const int* in_sizes, int n_in,
                              void* d_out, int out_size, void* d_ws, size_t ws_size,
                              hipStream_t stream) {
    const float* ue    = (const float*)d_in[0];  // [NU, 64]
    const float* ie    = (const float*)d_in[1];  // [NI, 64]
    const float* fw    = (const float*)d_in[2];  // [4, 4]
    const int*   eu    = (const int*)d_in[3];    // [E]
    const int*   eitem = (const int*)d_in[4];    // [E]
    const int*   users = (const int*)d_in[5];    // [B]
    const int*   items = (const int*)d_in[6];    // [B]
    float* scores = (float*)d_out;               // [B]

    const size_t xbytes = (size_t)NN_ * D_ * sizeof(float);   // 179.2 MB
    const size_t zbytes = (size_t)B_ * D_ * sizeof(float);    // 33.55 MB

    char* ws = (char*)d_ws;
    float* XA   = (float*)ws;                 ws += xbytes;
    float* XB   = (float*)ws;                 ws += xbytes;
    float* Zu   = (float*)ws;                 ws += zbytes;
    float* Zi   = (float*)ws;                 ws += zbytes;
    float* degf = (float*)ws;                 ws += (size_t)NN_ * sizeof(float);

    // 1. degrees -> inv_sqrt (recomputed every call; deterministic integer counts)
    hipMemsetAsync(degf, 0, (size_t)NN_ * sizeof(float), stream);
    deg_kernel<<<(E_ + 255) / 256, 256, 0, stream>>>(eu, eitem, degf);
    inv_kernel<<<(NN_ + 255) / 256, 256, 0, stream>>>(degf);

    // 2. Z accumulators start at layer-0 embeddings of the gathered rows
    zinit_kernel<<<(2 * B_ * D_) / 256, 256, 0, stream>>>(ue, ie, users, items, Zu, Zi);

    // 3. three propagation layers; layer 0 reads the input embeddings directly
    const float* curSrc = ue;
    const float* curDst = ie - (size_t)NU_ * D_;  // so that index (ei+NU)*64 lands in item_emb
    float* nxt = XA;
    float* other = XB;
    for (int l = 0; l < 3; ++l) {
        hipMemsetAsync(nxt, 0, xbytes, stream);
        prop_kernel<<<(E_ * D_) / 256, 256, 0, stream>>>(curSrc, curDst, eu, eitem, degf, nxt);
        zacc_kernel<<<(2 * B_ * D_) / 256, 256, 0, stream>>>(nxt, users, items, Zu, Zi);
        curSrc = nxt;
        curDst = nxt;
        float* tmp = other; other = nxt; nxt = tmp;
    }

    // 4. factor-correlation scores
    score_kernel<<<(B_ * D_) / 256, 256, 0, stream>>>(Zu, Zi, fw, scores);
}

// Round 2
// 1638.872 us; speedup vs baseline: 1.7931x; 1.7931x over previous
//
#include <hip/hip_runtime.h>
#include <math.h>

// Problem constants (match reference)
#define NU_ 500000
#define NI_ 200000
#define NN_ 700000            // NU + NI
#define D_  64
#define E_  2000000
#define B_  131072
#define TWO_E 4000000

// ---------------------------------------------------------------------------
// Integer degree histogram (both endpoints of every edge).
__global__ __launch_bounds__(256) void deg_kernel(const int* __restrict__ eu,
                                                  const int* __restrict__ ei,
                                                  int* __restrict__ deg) {
    int e = blockIdx.x * 256 + threadIdx.x;
    if (e >= E_) return;
    atomicAdd(&deg[eu[e]], 1);
    atomicAdd(&deg[NU_ + ei[e]], 1);
}

__global__ __launch_bounds__(256) void inv_kernel(const int* __restrict__ deg,
                                                  float* __restrict__ inv) {
    int v = blockIdx.x * 256 + threadIdx.x;
    if (v >= NN_) return;
    int d = deg[v];
    inv[v] = (d > 0) ? (1.0f / sqrtf((float)d)) : 0.0f;
}

// ---------------------------------------------------------------------------
// Two-level exclusive scan (1024 elements per block, Hillis-Steele in LDS).
__global__ __launch_bounds__(1024) void scan_block(const int* __restrict__ in, int n,
                                                   int* __restrict__ out,
                                                   int* __restrict__ psum) {
    __shared__ int lds[1024];
    int g = blockIdx.x * 1024 + threadIdx.x;
    int v = (g < n) ? in[g] : 0;
    lds[threadIdx.x] = v;
    __syncthreads();
    for (int off = 1; off < 1024; off <<= 1) {
        int t = (threadIdx.x >= (unsigned)off) ? lds[threadIdx.x - off] : 0;
        __syncthreads();
        lds[threadIdx.x] += t;
        __syncthreads();
    }
    if (g < n) out[g] = lds[threadIdx.x] - v;     // exclusive
    if (threadIdx.x == 1023 && psum) psum[blockIdx.x] = lds[1023];
}

__global__ __launch_bounds__(256) void scan_add(int* __restrict__ rowptr,
                                                const int* __restrict__ poff) {
    int g = blockIdx.x * 256 + threadIdx.x;
    if (g < NN_) rowptr[g] += poff[g >> 10];
    if (g == 0) rowptr[NN_] = TWO_E;              // total is statically known
}

// ---------------------------------------------------------------------------
// CSR fill: adj holds neighbor node-ids (0..NN). Order within a bucket is
// nondeterministic (atomic cursor) — only permutes fp summation order.
__global__ __launch_bounds__(256) void fill_kernel(const int* __restrict__ eu,
                                                   const int* __restrict__ ei,
                                                   int* __restrict__ cursor,
                                                   int* __restrict__ adj) {
    int e = blockIdx.x * 256 + threadIdx.x;
    if (e >= E_) return;
    int su = eu[e];
    int sv = ei[e] + NU_;
    int p = atomicAdd(&cursor[su], 1);
    adj[p] = sv;
    int q = atomicAdd(&cursor[sv], 1);
    adj[q] = su;
}

// ---------------------------------------------------------------------------
// Pull-based propagate: one wave per node v, lane d = feature.
// out[v][d] = inv[v] * sum_n inv[n] * x[n][d]
// Row address for neighbor n: (n < NU ? xu : xio) + n*64  (xio pre-offset by -NU*64).
__global__ __launch_bounds__(256) void pull_kernel(const float* __restrict__ xu,
                                                   const float* __restrict__ xio,
                                                   const float* __restrict__ inv,
                                                   const int* __restrict__ rowptr,
                                                   const int* __restrict__ adj,
                                                   float* __restrict__ out) {
    int t = blockIdx.x * 256 + threadIdx.x;
    int v = t >> 6;
    int d = t & 63;
    int beg = rowptr[v];
    int end = rowptr[v + 1];
    float s = 0.0f;
    int j = beg;
    for (; j + 1 < end; j += 2) {               // 2x unroll to overlap gathers
        int n0 = adj[j];
        int n1 = adj[j + 1];
        const float* r0 = (n0 < NU_ ? xu : xio) + (size_t)n0 * D_;
        const float* r1 = (n1 < NU_ ? xu : xio) + (size_t)n1 * D_;
        float w0 = inv[n0];
        float w1 = inv[n1];
        s += w0 * r0[d];
        s += w1 * r1[d];
    }
    if (j < end) {
        int n0 = adj[j];
        const float* r0 = (n0 < NU_ ? xu : xio) + (size_t)n0 * D_;
        s += inv[n0] * r0[d];
    }
    out[(size_t)v * D_ + d] = inv[v] * s;
}

// ---------------------------------------------------------------------------
// Final layer fused: pull only the gathered rows, accumulate straight into Z.
__global__ __launch_bounds__(256) void pullz_kernel(const float* __restrict__ x,
                                                    const float* __restrict__ inv,
                                                    const int* __restrict__ rowptr,
                                                    const int* __restrict__ adj,
                                                    const int* __restrict__ users,
                                                    const int* __restrict__ items,
                                                    float* __restrict__ Zu,
                                                    float* __restrict__ Zi) {
    int t = blockIdx.x * 256 + threadIdx.x;
    int b = t >> 6;
    int d = t & 63;
    int node;
    float* Z;
    if (b < B_) { node = users[b];           Z = Zu + (size_t)b * D_; }
    else        { node = items[b - B_] + NU_; Z = Zi + (size_t)(b - B_) * D_; }
    int beg = rowptr[node];
    int end = rowptr[node + 1];
    float s = 0.0f;
    int j = beg;
    for (; j + 1 < end; j += 2) {
        int n0 = adj[j];
        int n1 = adj[j + 1];
        float w0 = inv[n0];
        float w1 = inv[n1];
        s += w0 * x[(size_t)n0 * D_ + d];
        s += w1 * x[(size_t)n1 * D_ + d];
    }
    if (j < end) {
        int n0 = adj[j];
        s += inv[n0] * x[(size_t)n0 * D_ + d];
    }
    Z[d] += inv[node] * s;
}

// ---------------------------------------------------------------------------
__global__ __launch_bounds__(256) void zinit_kernel(const float* __restrict__ ue,
                                                    const float* __restrict__ ie,
                                                    const int* __restrict__ users,
                                                    const int* __restrict__ items,
                                                    float* __restrict__ Zu,
                                                    float* __restrict__ Zi) {
    int t = blockIdx.x * 256 + threadIdx.x;
    int b = t >> 6;
    int d = t & 63;
    if (b < B_) {
        Zu[(size_t)b * D_ + d] = ue[(size_t)users[b] * D_ + d];
    } else {
        int bb = b - B_;
        Zi[(size_t)bb * D_ + d] = ie[(size_t)items[bb] * D_ + d];
    }
}

__global__ __launch_bounds__(256) void zacc_kernel(const float* __restrict__ x,
                                                   const int* __restrict__ users,
                                                   const int* __restrict__ items,
                                                   float* __restrict__ Zu,
                                                   float* __restrict__ Zi) {
    int t = blockIdx.x * 256 + threadIdx.x;
    int b = t >> 6;
    int d = t & 63;
    if (b < B_) {
        Zu[(size_t)b * D_ + d] += x[(size_t)users[b] * D_ + d];
    } else {
        int bb = b - B_;
        Zi[(size_t)bb * D_ + d] += x[((size_t)items[bb] + NU_) * D_ + d];
    }
}

// ---------------------------------------------------------------------------
// One wave per pair b. Lane l: f = l>>4, d = l&15.
__global__ __launch_bounds__(256) void score_kernel(const float* __restrict__ Zu,
                                                    const float* __restrict__ Zi,
                                                    const float* __restrict__ fw,
                                                    float* __restrict__ out) {
    int t = blockIdx.x * 256 + threadIdx.x;
    int b = t >> 6;
    int l = t & 63;
    int f = l >> 4;
    int dd = l & 15;
    float pu = Zu[(size_t)b * D_ + l];
    float s = 0.0f;
#pragma unroll
    for (int g = 0; g < 4; ++g) {
        float pi = Zi[(size_t)b * D_ + g * 16 + dd];
        float p = pu * pi;
        p += __shfl_xor(p, 1);
        p += __shfl_xor(p, 2);
        p += __shfl_xor(p, 4);
        p += __shfl_xor(p, 8);
        s += fw[f * 4 + g] * p;
    }
    s += __shfl_xor(s, 16);
    s += __shfl_xor(s, 32);
    if (l == 0) out[b] = s * 0.0625f;  // (1/4)*(1/4) layer-mean scaling
}

// ---------------------------------------------------------------------------
extern "C" void kernel_launch(void* const* d_in, const int* in_sizes, int n_in,
                              void* d_out, int out_size, void* d_ws, size_t ws_size,
                              hipStream_t stream) {
    const float* ue    = (const float*)d_in[0];  // [NU, 64]
    const float* ie    = (const float*)d_in[1];  // [NI, 64]
    const float* fw    = (const float*)d_in[2];  // [4, 4]
    const int*   eu    = (const int*)d_in[3];    // [E]
    const int*   eitem = (const int*)d_in[4];    // [E]
    const int*   users = (const int*)d_in[5];    // [B]
    const int*   items = (const int*)d_in[6];    // [B]
    float* scores = (float*)d_out;               // [B]

    const size_t xbytes = (size_t)NN_ * D_ * sizeof(float);   // 179.2 MB
    const size_t zbytes = (size_t)B_ * D_ * sizeof(float);    // 33.55 MB
    const int NB_SCAN = (NN_ + 1023) / 1024;                  // 684

    char* ws = (char*)d_ws;
    float* XA     = (float*)ws;  ws += xbytes;
    float* XB     = (float*)ws;  ws += xbytes;
    float* Zu     = (float*)ws;  ws += zbytes;
    float* Zi     = (float*)ws;  ws += zbytes;
    float* inv    = (float*)ws;  ws += (size_t)NN_ * 4;
    int*   deg    = (int*)ws;    ws += (size_t)NN_ * 4;
    int*   rowptr = (int*)ws;    ws += (size_t)(NN_ + 1) * 4;
    int*   cursor = (int*)ws;    ws += (size_t)NN_ * 4;
    int*   adj    = (int*)ws;    ws += (size_t)TWO_E * 4;     // 16 MB
    int*   psum   = (int*)ws;    ws += (size_t)NB_SCAN * 4;
    int*   poff   = (int*)ws;    ws += (size_t)NB_SCAN * 4;

    // --- CSR build -----------------------------------------------------
    hipMemsetAsync(deg, 0, (size_t)NN_ * 4, stream);
    deg_kernel<<<(E_ + 255) / 256, 256, 0, stream>>>(eu, eitem, deg);
    inv_kernel<<<(NN_ + 255) / 256, 256, 0, stream>>>(deg, inv);
    scan_block<<<NB_SCAN, 1024, 0, stream>>>(deg, NN_, rowptr, psum);
    scan_block<<<1, 1024, 0, stream>>>(psum, NB_SCAN, poff, (int*)nullptr);
    scan_add<<<(NN_ + 255) / 256, 256, 0, stream>>>(rowptr, poff);
    hipMemcpyAsync(cursor, rowptr, (size_t)NN_ * 4, hipMemcpyDeviceToDevice, stream);
    fill_kernel<<<(E_ + 255) / 256, 256, 0, stream>>>(eu, eitem, cursor, adj);

    // --- Z init at layer-0 embeddings ----------------------------------
    zinit_kernel<<<(2 * B_ * D_) / 256, 256, 0, stream>>>(ue, ie, users, items, Zu, Zi);

    // --- 3 propagation layers (pull) -----------------------------------
    // Layer 1: source is the (virtually concatenated) input embeddings.
    pull_kernel<<<(NN_ * D_) / 256, 256, 0, stream>>>(
        ue, ie - (size_t)NU_ * D_, inv, rowptr, adj, XA);
    zacc_kernel<<<(2 * B_ * D_) / 256, 256, 0, stream>>>(XA, users, items, Zu, Zi);
    // Layer 2: XA holds the full concatenated X.
    pull_kernel<<<(NN_ * D_) / 256, 256, 0, stream>>>(
        XA, XA, inv, rowptr, adj, XB);
    zacc_kernel<<<(2 * B_ * D_) / 256, 256, 0, stream>>>(XB, users, items, Zu, Zi);
    // Layer 3: only the gathered rows are needed — fuse into Z.
    pullz_kernel<<<(2 * B_ * D_) / 256, 256, 0, stream>>>(
        XB, inv, rowptr, adj, users, items, Zu, Zi);

    // --- scores --------------------------------------------------------
    score_kernel<<<(B_ * D_) / 256, 256, 0, stream>>>(Zu, Zi, fw, scores);
}

// Round 3
// 1307.263 us; speedup vs baseline: 2.2479x; 1.2537x over previous
//
#include <hip/hip_runtime.h>
#include <math.h>

// Problem constants (match reference)
#define NU_ 500000
#define NI_ 200000
#define NN_ 700000            // NU + NI
#define D_  64
#define E_  2000000
#define B_  131072
#define TWO_E 4000000

// ---------------------------------------------------------------------------
// Integer degree histogram (both endpoints of every edge).
__global__ __launch_bounds__(256) void deg_kernel(const int* __restrict__ eu,
                                                  const int* __restrict__ ei,
                                                  int* __restrict__ deg) {
    int e = blockIdx.x * 256 + threadIdx.x;
    if (e >= E_) return;
    atomicAdd(&deg[eu[e]], 1);
    atomicAdd(&deg[NU_ + ei[e]], 1);
}

__global__ __launch_bounds__(256) void inv_kernel(const int* __restrict__ deg,
                                                  float* __restrict__ inv) {
    int v = blockIdx.x * 256 + threadIdx.x;
    if (v >= NN_) return;
    int d = deg[v];
    inv[v] = (d > 0) ? (1.0f / sqrtf((float)d)) : 0.0f;
}

// ---------------------------------------------------------------------------
// Two-level exclusive scan (1024 elements per block, Hillis-Steele in LDS).
__global__ __launch_bounds__(1024) void scan_block(const int* __restrict__ in, int n,
                                                   int* __restrict__ out,
                                                   int* __restrict__ psum) {
    __shared__ int lds[1024];
    int g = blockIdx.x * 1024 + threadIdx.x;
    int v = (g < n) ? in[g] : 0;
    lds[threadIdx.x] = v;
    __syncthreads();
    for (int off = 1; off < 1024; off <<= 1) {
        int t = (threadIdx.x >= (unsigned)off) ? lds[threadIdx.x - off] : 0;
        __syncthreads();
        lds[threadIdx.x] += t;
        __syncthreads();
    }
    if (g < n) out[g] = lds[threadIdx.x] - v;     // exclusive
    if (threadIdx.x == 1023 && psum) psum[blockIdx.x] = lds[1023];
}

__global__ __launch_bounds__(256) void scan_add(int* __restrict__ rowptr,
                                                const int* __restrict__ poff) {
    int g = blockIdx.x * 256 + threadIdx.x;
    if (g < NN_) rowptr[g] += poff[g >> 10];
    if (g == 0) rowptr[NN_] = TWO_E;              // total is statically known
}

// ---------------------------------------------------------------------------
// CSR fill: adj holds neighbor node-ids (0..NN). Order within a bucket is
// nondeterministic (atomic cursor) — only permutes fp summation order.
__global__ __launch_bounds__(256) void fill_kernel(const int* __restrict__ eu,
                                                   const int* __restrict__ ei,
                                                   int* __restrict__ cursor,
                                                   int* __restrict__ adj) {
    int e = blockIdx.x * 256 + threadIdx.x;
    if (e >= E_) return;
    int su = eu[e];
    int sv = ei[e] + NU_;
    int p = atomicAdd(&cursor[su], 1);
    adj[p] = sv;
    int q = atomicAdd(&cursor[sv], 1);
    adj[q] = su;
}

// ---------------------------------------------------------------------------
// Pull-based propagate, MLP-heavy layout:
//   wave = one node v; lane = g*16+q; g = neighbor slot (4), q = float4 quad.
//   Each iteration gathers 8 neighbor rows (2-deep unroll x 4 slots) with
//   dwordx4 loads -> 8 x 256B rows in flight per wave.
// out[v][:] = inv[v] * sum_n inv[n] * x[n][:]
// Row address for neighbor n: (n < NU ? xu : xio) + n*64 (xio pre-offset -NU*64).
__global__ __launch_bounds__(256) void pull_kernel(const float* __restrict__ xu,
                                                   const float* __restrict__ xio,
                                                   const float* __restrict__ inv,
                                                   const int* __restrict__ rowptr,
                                                   const int* __restrict__ adj,
                                                   float* __restrict__ out) {
    int t = blockIdx.x * 256 + threadIdx.x;
    int v = t >> 6;
    int lane = t & 63;
    int g = lane >> 4;        // neighbor slot
    int q = lane & 15;        // feature quad (features 4q..4q+3)
    int beg = rowptr[v];
    int end = rowptr[v + 1];
    float sx = 0.f, sy = 0.f, sz = 0.f, sw = 0.f;
    for (int j = beg; j < end; j += 8) {
        int i0 = j + g;
        int i1 = j + 4 + g;
        int n0 = (i0 < end) ? adj[i0] : 0;
        int n1 = (i1 < end) ? adj[i1] : 0;
        float w0 = (i0 < end) ? inv[n0] : 0.0f;
        float w1 = (i1 < end) ? inv[n1] : 0.0f;
        const float4* r0 = (const float4*)((n0 < NU_ ? xu : xio) + (size_t)n0 * D_) + q;
        const float4* r1 = (const float4*)((n1 < NU_ ? xu : xio) + (size_t)n1 * D_) + q;
        float4 a = *r0;
        float4 b = *r1;
        sx += w0 * a.x + w1 * b.x;
        sy += w0 * a.y + w1 * b.y;
        sz += w0 * a.z + w1 * b.z;
        sw += w0 * a.w + w1 * b.w;
    }
    // combine the 4 neighbor slots (lanes q, q+16, q+32, q+48)
    sx += __shfl_xor(sx, 16); sy += __shfl_xor(sy, 16);
    sz += __shfl_xor(sz, 16); sw += __shfl_xor(sw, 16);
    sx += __shfl_xor(sx, 32); sy += __shfl_xor(sy, 32);
    sz += __shfl_xor(sz, 32); sw += __shfl_xor(sw, 32);
    if (g == 0) {
        float iv = inv[v];
        float4 o; o.x = iv * sx; o.y = iv * sy; o.z = iv * sz; o.w = iv * sw;
        ((float4*)(out + (size_t)v * D_))[q] = o;
    }
}

// ---------------------------------------------------------------------------
// Final layer fused: pull only the gathered rows, accumulate straight into Z.
__global__ __launch_bounds__(256) void pullz_kernel(const float* __restrict__ x,
                                                    const float* __restrict__ inv,
                                                    const int* __restrict__ rowptr,
                                                    const int* __restrict__ adj,
                                                    const int* __restrict__ users,
                                                    const int* __restrict__ items,
                                                    float* __restrict__ Zu,
                                                    float* __restrict__ Zi) {
    int t = blockIdx.x * 256 + threadIdx.x;
    int b = t >> 6;
    int lane = t & 63;
    int g = lane >> 4;
    int q = lane & 15;
    int node;
    float* Z;
    if (b < B_) { node = users[b];            Z = Zu + (size_t)b * D_; }
    else        { node = items[b - B_] + NU_; Z = Zi + (size_t)(b - B_) * D_; }
    int beg = rowptr[node];
    int end = rowptr[node + 1];
    float sx = 0.f, sy = 0.f, sz = 0.f, sw = 0.f;
    for (int j = beg; j < end; j += 8) {
        int i0 = j + g;
        int i1 = j + 4 + g;
        int n0 = (i0 < end) ? adj[i0] : 0;
        int n1 = (i1 < end) ? adj[i1] : 0;
        float w0 = (i0 < end) ? inv[n0] : 0.0f;
        float w1 = (i1 < end) ? inv[n1] : 0.0f;
        const float4* r0 = (const float4*)(x + (size_t)n0 * D_) + q;
        const float4* r1 = (const float4*)(x + (size_t)n1 * D_) + q;
        float4 a = *r0;
        float4 b4 = *r1;
        sx += w0 * a.x + w1 * b4.x;
        sy += w0 * a.y + w1 * b4.y;
        sz += w0 * a.z + w1 * b4.z;
        sw += w0 * a.w + w1 * b4.w;
    }
    sx += __shfl_xor(sx, 16); sy += __shfl_xor(sy, 16);
    sz += __shfl_xor(sz, 16); sw += __shfl_xor(sw, 16);
    sx += __shfl_xor(sx, 32); sy += __shfl_xor(sy, 32);
    sz += __shfl_xor(sz, 32); sw += __shfl_xor(sw, 32);
    if (g == 0) {
        float iv = inv[node];
        float4* zp = (float4*)Z + q;
        float4 z = *zp;
        z.x += iv * sx; z.y += iv * sy; z.z += iv * sz; z.w += iv * sw;
        *zp = z;
    }
}

// ---------------------------------------------------------------------------
// float4 Z kernels: thread handles one quad. t covers 2B*16 threads.
__global__ __launch_bounds__(256) void zinit_kernel(const float* __restrict__ ue,
                                                    const float* __restrict__ ie,
                                                    const int* __restrict__ users,
                                                    const int* __restrict__ items,
                                                    float* __restrict__ Zu,
                                                    float* __restrict__ Zi) {
    int t = blockIdx.x * 256 + threadIdx.x;
    int b = t >> 4;
    int q = t & 15;
    if (b < B_) {
        ((float4*)(Zu + (size_t)b * D_))[q] =
            ((const float4*)(ue + (size_t)users[b] * D_))[q];
    } else {
        int bb = b - B_;
        ((float4*)(Zi + (size_t)bb * D_))[q] =
            ((const float4*)(ie + (size_t)items[bb] * D_))[q];
    }
}

__global__ __launch_bounds__(256) void zacc_kernel(const float* __restrict__ x,
                                                   const int* __restrict__ users,
                                                   const int* __restrict__ items,
                                                   float* __restrict__ Zu,
                                                   float* __restrict__ Zi) {
    int t = blockIdx.x * 256 + threadIdx.x;
    int b = t >> 4;
    int q = t & 15;
    float4* zp;
    const float4* xp;
    if (b < B_) {
        zp = (float4*)(Zu + (size_t)b * D_) + q;
        xp = (const float4*)(x + (size_t)users[b] * D_) + q;
    } else {
        int bb = b - B_;
        zp = (float4*)(Zi + (size_t)bb * D_) + q;
        xp = (const float4*)(x + ((size_t)items[bb] + NU_) * D_) + q;
    }
    float4 z = *zp, a = *xp;
    z.x += a.x; z.y += a.y; z.z += a.z; z.w += a.w;
    *zp = z;
}

// ---------------------------------------------------------------------------
// One wave per pair b. Lane l: f = l>>4, d = l&15.
__global__ __launch_bounds__(256) void score_kernel(const float* __restrict__ Zu,
                                                    const float* __restrict__ Zi,
                                                    const float* __restrict__ fw,
                                                    float* __restrict__ out) {
    int t = blockIdx.x * 256 + threadIdx.x;
    int b = t >> 6;
    int l = t & 63;
    int f = l >> 4;
    int dd = l & 15;
    float pu = Zu[(size_t)b * D_ + l];
    float s = 0.0f;
#pragma unroll
    for (int g = 0; g < 4; ++g) {
        float pi = Zi[(size_t)b * D_ + g * 16 + dd];
        float p = pu * pi;
        p += __shfl_xor(p, 1);
        p += __shfl_xor(p, 2);
        p += __shfl_xor(p, 4);
        p += __shfl_xor(p, 8);
        s += fw[f * 4 + g] * p;
    }
    s += __shfl_xor(s, 16);
    s += __shfl_xor(s, 32);
    if (l == 0) out[b] = s * 0.0625f;  // (1/4)*(1/4) layer-mean scaling
}

// ---------------------------------------------------------------------------
extern "C" void kernel_launch(void* const* d_in, const int* in_sizes, int n_in,
                              void* d_out, int out_size, void* d_ws, size_t ws_size,
                              hipStream_t stream) {
    const float* ue    = (const float*)d_in[0];  // [NU, 64]
    const float* ie    = (const float*)d_in[1];  // [NI, 64]
    const float* fw    = (const float*)d_in[2];  // [4, 4]
    const int*   eu    = (const int*)d_in[3];    // [E]
    const int*   eitem = (const int*)d_in[4];    // [E]
    const int*   users = (const int*)d_in[5];    // [B]
    const int*   items = (const int*)d_in[6];    // [B]
    float* scores = (float*)d_out;               // [B]

    const size_t xbytes = (size_t)NN_ * D_ * sizeof(float);   // 179.2 MB
    const size_t zbytes = (size_t)B_ * D_ * sizeof(float);    // 33.55 MB
    const int NB_SCAN = (NN_ + 1023) / 1024;                  // 684

    char* ws = (char*)d_ws;
    float* XA     = (float*)ws;  ws += xbytes;
    float* XB     = (float*)ws;  ws += xbytes;
    float* Zu     = (float*)ws;  ws += zbytes;
    float* Zi     = (float*)ws;  ws += zbytes;
    float* inv    = (float*)ws;  ws += (size_t)NN_ * 4;
    int*   deg    = (int*)ws;    ws += (size_t)NN_ * 4;
    int*   rowptr = (int*)ws;    ws += (size_t)(NN_ + 1) * 4;
    int*   cursor = (int*)ws;    ws += (size_t)NN_ * 4;
    int*   adj    = (int*)ws;    ws += (size_t)TWO_E * 4;     // 16 MB
    int*   psum   = (int*)ws;    ws += (size_t)NB_SCAN * 4;
    int*   poff   = (int*)ws;    ws += (size_t)NB_SCAN * 4;

    // --- CSR build -----------------------------------------------------
    hipMemsetAsync(deg, 0, (size_t)NN_ * 4, stream);
    deg_kernel<<<(E_ + 255) / 256, 256, 0, stream>>>(eu, eitem, deg);
    inv_kernel<<<(NN_ + 255) / 256, 256, 0, stream>>>(deg, inv);
    scan_block<<<NB_SCAN, 1024, 0, stream>>>(deg, NN_, rowptr, psum);
    scan_block<<<1, 1024, 0, stream>>>(psum, NB_SCAN, poff, (int*)nullptr);
    scan_add<<<(NN_ + 255) / 256, 256, 0, stream>>>(rowptr, poff);
    hipMemcpyAsync(cursor, rowptr, (size_t)NN_ * 4, hipMemcpyDeviceToDevice, stream);
    fill_kernel<<<(E_ + 255) / 256, 256, 0, stream>>>(eu, eitem, cursor, adj);

    // --- Z init at layer-0 embeddings ----------------------------------
    zinit_kernel<<<(2 * B_ * 16) / 256, 256, 0, stream>>>(ue, ie, users, items, Zu, Zi);

    // --- 3 propagation layers (pull) -----------------------------------
    pull_kernel<<<(NN_ * D_) / 256, 256, 0, stream>>>(
        ue, ie - (size_t)NU_ * D_, inv, rowptr, adj, XA);
    zacc_kernel<<<(2 * B_ * 16) / 256, 256, 0, stream>>>(XA, users, items, Zu, Zi);
    pull_kernel<<<(NN_ * D_) / 256, 256, 0, stream>>>(
        XA, XA, inv, rowptr, adj, XB);
    zacc_kernel<<<(2 * B_ * 16) / 256, 256, 0, stream>>>(XB, users, items, Zu, Zi);
    // Layer 3: only the gathered rows are needed — fuse into Z.
    pullz_kernel<<<(2 * B_ * D_) / 256, 256, 0, stream>>>(
        XB, inv, rowptr, adj, users, items, Zu, Zi);

    // --- scores --------------------------------------------------------
    score_kernel<<<(B_ * D_) / 256, 256, 0, stream>>>(Zu, Zi, fw, scores);
}

// Round 4
// 1178.436 us; speedup vs baseline: 2.4936x; 1.1093x over previous
//
#include <hip/hip_runtime.h>
#include <math.h>

// Problem constants (match reference)
#define NU_ 500000
#define NI_ 200000
#define NN_ 700000            // NU + NI
#define D_  64
#define E_  2000000
#define B_  131072
#define TWO_E 4000000
#define PAD_ 32               // counters padded to one per 128B line

// ---------------------------------------------------------------------------
// Degree histogram + rank assignment in one pass.
// degp is padded (stride PAD_ ints = 128B) to avoid cross-XCD false sharing.
// The atomic return value IS the edge's rank within its endpoint's bucket.
__global__ __launch_bounds__(256) void deg_rank_kernel(const int* __restrict__ eu,
                                                       const int* __restrict__ ei,
                                                       int* __restrict__ degp,
                                                       int* __restrict__ ru,
                                                       int* __restrict__ rv) {
    int e = blockIdx.x * 256 + threadIdx.x;
    if (e >= E_) return;
    int su = eu[e];
    int sv = ei[e] + NU_;
    ru[e] = atomicAdd(&degp[(size_t)su * PAD_], 1);
    rv[e] = atomicAdd(&degp[(size_t)sv * PAD_], 1);
}

// Compact padded degrees -> deg[] (for scan) and inv_sqrt[].
__global__ __launch_bounds__(256) void compact_inv_kernel(const int* __restrict__ degp,
                                                          int* __restrict__ deg,
                                                          float* __restrict__ inv) {
    int v = blockIdx.x * 256 + threadIdx.x;
    if (v >= NN_) return;
    int d = degp[(size_t)v * PAD_];
    deg[v] = d;
    inv[v] = (d > 0) ? (1.0f / sqrtf((float)d)) : 0.0f;
}

// ---------------------------------------------------------------------------
// Two-level exclusive scan (1024 elements per block, Hillis-Steele in LDS).
__global__ __launch_bounds__(1024) void scan_block(const int* __restrict__ in, int n,
                                                   int* __restrict__ out,
                                                   int* __restrict__ psum) {
    __shared__ int lds[1024];
    int g = blockIdx.x * 1024 + threadIdx.x;
    int v = (g < n) ? in[g] : 0;
    lds[threadIdx.x] = v;
    __syncthreads();
    for (int off = 1; off < 1024; off <<= 1) {
        int t = (threadIdx.x >= (unsigned)off) ? lds[threadIdx.x - off] : 0;
        __syncthreads();
        lds[threadIdx.x] += t;
        __syncthreads();
    }
    if (g < n) out[g] = lds[threadIdx.x] - v;     // exclusive
    if (threadIdx.x == 1023 && psum) psum[blockIdx.x] = lds[1023];
}

__global__ __launch_bounds__(256) void scan_add(int* __restrict__ rowptr,
                                                const int* __restrict__ poff) {
    int g = blockIdx.x * 256 + threadIdx.x;
    if (g < NN_) rowptr[g] += poff[g >> 10];
    if (g == 0) rowptr[NN_] = TWO_E;              // total is statically known
}

// ---------------------------------------------------------------------------
// Atomic-free CSR fill: position = rowptr[node] + precomputed rank.
// Pure coalesced reads + fire-and-forget scattered stores.
__global__ __launch_bounds__(256) void fill2_kernel(const int* __restrict__ eu,
                                                    const int* __restrict__ ei,
                                                    const int* __restrict__ ru,
                                                    const int* __restrict__ rv,
                                                    const int* __restrict__ rowptr,
                                                    int* __restrict__ adj) {
    int e = blockIdx.x * 256 + threadIdx.x;
    if (e >= E_) return;
    int su = eu[e];
    int sv = ei[e] + NU_;
    adj[rowptr[su] + ru[e]] = sv;
    adj[rowptr[sv] + rv[e]] = su;
}

// ---------------------------------------------------------------------------
// Pull-based propagate, MLP-heavy layout:
//   wave = one node v; lane = g*16+q; g = neighbor slot (4), q = float4 quad.
//   4-deep unroll x 4 slots -> 16 neighbor rows in flight per wave.
//   Masked slots gather row 0 with weight 0 (L1-resident after first hit).
__global__ __launch_bounds__(256) void pull_kernel(const float* __restrict__ xu,
                                                   const float* __restrict__ xio,
                                                   const float* __restrict__ inv,
                                                   const int* __restrict__ rowptr,
                                                   const int* __restrict__ adj,
                                                   float* __restrict__ out) {
    int t = blockIdx.x * 256 + threadIdx.x;
    int v = t >> 6;
    int lane = t & 63;
    int g = lane >> 4;        // neighbor slot
    int q = lane & 15;        // feature quad (features 4q..4q+3)
    int beg = rowptr[v];
    int end = rowptr[v + 1];
    float sx = 0.f, sy = 0.f, sz = 0.f, sw = 0.f;
    for (int j = beg; j < end; j += 16) {
#pragma unroll
        for (int u = 0; u < 4; ++u) {
            int i = j + 4 * u + g;
            int n = (i < end) ? adj[i] : 0;
            float w = (i < end) ? inv[n] : 0.0f;
            float4 a = *((const float4*)((n < NU_ ? xu : xio) + (size_t)n * D_) + q);
            sx += w * a.x;
            sy += w * a.y;
            sz += w * a.z;
            sw += w * a.w;
        }
    }
    // combine the 4 neighbor slots (lanes q, q+16, q+32, q+48)
    sx += __shfl_xor(sx, 16); sy += __shfl_xor(sy, 16);
    sz += __shfl_xor(sz, 16); sw += __shfl_xor(sw, 16);
    sx += __shfl_xor(sx, 32); sy += __shfl_xor(sy, 32);
    sz += __shfl_xor(sz, 32); sw += __shfl_xor(sw, 32);
    if (g == 0) {
        float iv = inv[v];
        float4 o; o.x = iv * sx; o.y = iv * sy; o.z = iv * sz; o.w = iv * sw;
        ((float4*)(out + (size_t)v * D_))[q] = o;
    }
}

// ---------------------------------------------------------------------------
// Final layer fused: pull only the gathered rows, accumulate straight into Z.
__global__ __launch_bounds__(256) void pullz_kernel(const float* __restrict__ x,
                                                    const float* __restrict__ inv,
                                                    const int* __restrict__ rowptr,
                                                    const int* __restrict__ adj,
                                                    const int* __restrict__ users,
                                                    const int* __restrict__ items,
                                                    float* __restrict__ Zu,
                                                    float* __restrict__ Zi) {
    int t = blockIdx.x * 256 + threadIdx.x;
    int b = t >> 6;
    int lane = t & 63;
    int g = lane >> 4;
    int q = lane & 15;
    int node;
    float* Z;
    if (b < B_) { node = users[b];            Z = Zu + (size_t)b * D_; }
    else        { node = items[b - B_] + NU_; Z = Zi + (size_t)(b - B_) * D_; }
    int beg = rowptr[node];
    int end = rowptr[node + 1];
    float sx = 0.f, sy = 0.f, sz = 0.f, sw = 0.f;
    for (int j = beg; j < end; j += 16) {
#pragma unroll
        for (int u = 0; u < 4; ++u) {
            int i = j + 4 * u + g;
            int n = (i < end) ? adj[i] : 0;
            float w = (i < end) ? inv[n] : 0.0f;
            float4 a = *((const float4*)(x + (size_t)n * D_) + q);
            sx += w * a.x;
            sy += w * a.y;
            sz += w * a.z;
            sw += w * a.w;
        }
    }
    sx += __shfl_xor(sx, 16); sy += __shfl_xor(sy, 16);
    sz += __shfl_xor(sz, 16); sw += __shfl_xor(sw, 16);
    sx += __shfl_xor(sx, 32); sy += __shfl_xor(sy, 32);
    sz += __shfl_xor(sz, 32); sw += __shfl_xor(sw, 32);
    if (g == 0) {
        float iv = inv[node];
        float4* zp = (float4*)Z + q;
        float4 z = *zp;
        z.x += iv * sx; z.y += iv * sy; z.z += iv * sz; z.w += iv * sw;
        *zp = z;
    }
}

// ---------------------------------------------------------------------------
// float4 Z kernels: thread handles one quad. t covers 2B*16 threads.
__global__ __launch_bounds__(256) void zinit_kernel(const float* __restrict__ ue,
                                                    const float* __restrict__ ie,
                                                    const int* __restrict__ users,
                                                    const int* __restrict__ items,
                                                    float* __restrict__ Zu,
                                                    float* __restrict__ Zi) {
    int t = blockIdx.x * 256 + threadIdx.x;
    int b = t >> 4;
    int q = t & 15;
    if (b < B_) {
        ((float4*)(Zu + (size_t)b * D_))[q] =
            ((const float4*)(ue + (size_t)users[b] * D_))[q];
    } else {
        int bb = b - B_;
        ((float4*)(Zi + (size_t)bb * D_))[q] =
            ((const float4*)(ie + (size_t)items[bb] * D_))[q];
    }
}

__global__ __launch_bounds__(256) void zacc_kernel(const float* __restrict__ x,
                                                   const int* __restrict__ users,
                                                   const int* __restrict__ items,
                                                   float* __restrict__ Zu,
                                                   float* __restrict__ Zi) {
    int t = blockIdx.x * 256 + threadIdx.x;
    int b = t >> 4;
    int q = t & 15;
    float4* zp;
    const float4* xp;
    if (b < B_) {
        zp = (float4*)(Zu + (size_t)b * D_) + q;
        xp = (const float4*)(x + (size_t)users[b] * D_) + q;
    } else {
        int bb = b - B_;
        zp = (float4*)(Zi + (size_t)bb * D_) + q;
        xp = (const float4*)(x + ((size_t)items[bb] + NU_) * D_) + q;
    }
    float4 z = *zp, a = *xp;
    z.x += a.x; z.y += a.y; z.z += a.z; z.w += a.w;
    *zp = z;
}

// ---------------------------------------------------------------------------
// One wave per pair b. Lane l: f = l>>4, d = l&15.
__global__ __launch_bounds__(256) void score_kernel(const float* __restrict__ Zu,
                                                    const float* __restrict__ Zi,
                                                    const float* __restrict__ fw,
                                                    float* __restrict__ out) {
    int t = blockIdx.x * 256 + threadIdx.x;
    int b = t >> 6;
    int l = t & 63;
    int f = l >> 4;
    int dd = l & 15;
    float pu = Zu[(size_t)b * D_ + l];
    float s = 0.0f;
#pragma unroll
    for (int g = 0; g < 4; ++g) {
        float pi = Zi[(size_t)b * D_ + g * 16 + dd];
        float p = pu * pi;
        p += __shfl_xor(p, 1);
        p += __shfl_xor(p, 2);
        p += __shfl_xor(p, 4);
        p += __shfl_xor(p, 8);
        s += fw[f * 4 + g] * p;
    }
    s += __shfl_xor(s, 16);
    s += __shfl_xor(s, 32);
    if (l == 0) out[b] = s * 0.0625f;  // (1/4)*(1/4) layer-mean scaling
}

// ---------------------------------------------------------------------------
extern "C" void kernel_launch(void* const* d_in, const int* in_sizes, int n_in,
                              void* d_out, int out_size, void* d_ws, size_t ws_size,
                              hipStream_t stream) {
    const float* ue    = (const float*)d_in[0];  // [NU, 64]
    const float* ie    = (const float*)d_in[1];  // [NI, 64]
    const float* fw    = (const float*)d_in[2];  // [4, 4]
    const int*   eu    = (const int*)d_in[3];    // [E]
    const int*   eitem = (const int*)d_in[4];    // [E]
    const int*   users = (const int*)d_in[5];    // [B]
    const int*   items = (const int*)d_in[6];    // [B]
    float* scores = (float*)d_out;               // [B]

    const size_t xbytes = (size_t)NN_ * D_ * sizeof(float);   // 179.2 MB
    const size_t zbytes = (size_t)B_ * D_ * sizeof(float);    // 33.55 MB
    const int NB_SCAN = (NN_ + 1023) / 1024;                  // 684

    char* ws = (char*)d_ws;
    float* XA     = (float*)ws;  ws += xbytes;
    float* XB     = (float*)ws;  ws += xbytes;
    float* Zu     = (float*)ws;  ws += zbytes;
    float* Zi     = (float*)ws;  ws += zbytes;
    float* inv    = (float*)ws;  ws += (size_t)NN_ * 4;
    int*   deg    = (int*)ws;    ws += (size_t)NN_ * 4;
    int*   rowptr = (int*)ws;    ws += (size_t)(NN_ + 1) * 4;
    int*   adj    = (int*)ws;    ws += (size_t)TWO_E * 4;     // 16 MB
    int*   psum   = (int*)ws;    ws += (size_t)NB_SCAN * 4;
    int*   poff   = (int*)ws;    ws += (size_t)NB_SCAN * 4;

    // Aliases (lifetimes are disjoint, stream-ordered):
    //  - padded counters degp live in XB (89.6 MB <= 179 MB); dead before
    //    layer-2 pull writes XB.
    //  - rank arrays ru/rv live in XA (16 MB); dead before layer-1 pull
    //    writes XA.
    int* degp = (int*)XB;
    int* ru   = (int*)XA;
    int* rv   = (int*)XA + E_;

    // --- CSR build (rank-from-degree, atomic-free fill) ----------------
    hipMemsetAsync(degp, 0, (size_t)NN_ * PAD_ * 4, stream);
    deg_rank_kernel<<<(E_ + 255) / 256, 256, 0, stream>>>(eu, eitem, degp, ru, rv);
    compact_inv_kernel<<<(NN_ + 255) / 256, 256, 0, stream>>>(degp, deg, inv);
    scan_block<<<NB_SCAN, 1024, 0, stream>>>(deg, NN_, rowptr, psum);
    scan_block<<<1, 1024, 0, stream>>>(psum, NB_SCAN, poff, (int*)nullptr);
    scan_add<<<(NN_ + 255) / 256, 256, 0, stream>>>(rowptr, poff);
    fill2_kernel<<<(E_ + 255) / 256, 256, 0, stream>>>(eu, eitem, ru, rv, rowptr, adj);

    // --- Z init at layer-0 embeddings ----------------------------------
    zinit_kernel<<<(2 * B_ * 16) / 256, 256, 0, stream>>>(ue, ie, users, items, Zu, Zi);

    // --- 3 propagation layers (pull) -----------------------------------
    pull_kernel<<<(NN_ * D_) / 256, 256, 0, stream>>>(
        ue, ie - (size_t)NU_ * D_, inv, rowptr, adj, XA);
    zacc_kernel<<<(2 * B_ * 16) / 256, 256, 0, stream>>>(XA, users, items, Zu, Zi);
    pull_kernel<<<(NN_ * D_) / 256, 256, 0, stream>>>(
        XA, XA, inv, rowptr, adj, XB);
    zacc_kernel<<<(2 * B_ * 16) / 256, 256, 0, stream>>>(XB, users, items, Zu, Zi);
    // Layer 3: only the gathered rows are needed — fuse into Z.
    pullz_kernel<<<(2 * B_ * D_) / 256, 256, 0, stream>>>(
        XB, inv, rowptr, adj, users, items, Zu, Zi);

    // --- scores --------------------------------------------------------
    score_kernel<<<(B_ * D_) / 256, 256, 0, stream>>>(Zu, Zi, fw, scores);
}

// Round 5
// 1065.314 us; speedup vs baseline: 2.7584x; 1.1062x over previous
//
#include <hip/hip_runtime.h>
#include <math.h>

// Problem constants (match reference)
#define NU_ 500000
#define NI_ 200000
#define NN_ 700000            // NU + NI
#define D_  64
#define E_  2000000
#define B_  131072
#define TWO_E 4000000
#define PAD_ 32               // counters padded to one per 128B line

typedef _Float16 half4 __attribute__((ext_vector_type(4)));  // 8 B

// ---------------------------------------------------------------------------
// Degree histogram + rank assignment in one pass.
// degp is padded (stride PAD_ ints = 128B) to avoid cross-XCD false sharing.
// The atomic return value IS the edge's rank within its endpoint's bucket.
__global__ __launch_bounds__(256) void deg_rank_kernel(const int* __restrict__ eu,
                                                       const int* __restrict__ ei,
                                                       int* __restrict__ degp,
                                                       int* __restrict__ ru,
                                                       int* __restrict__ rv) {
    int e = blockIdx.x * 256 + threadIdx.x;
    if (e >= E_) return;
    int su = eu[e];
    int sv = ei[e] + NU_;
    ru[e] = atomicAdd(&degp[(size_t)su * PAD_], 1);
    rv[e] = atomicAdd(&degp[(size_t)sv * PAD_], 1);
}

// Compact padded degrees -> deg[] (for scan) and inv_sqrt[].
__global__ __launch_bounds__(256) void compact_inv_kernel(const int* __restrict__ degp,
                                                          int* __restrict__ deg,
                                                          float* __restrict__ inv) {
    int v = blockIdx.x * 256 + threadIdx.x;
    if (v >= NN_) return;
    int d = degp[(size_t)v * PAD_];
    deg[v] = d;
    inv[v] = (d > 0) ? (1.0f / sqrtf((float)d)) : 0.0f;
}

// ---------------------------------------------------------------------------
// Convert the concatenated [ue; ie] f32 embeddings to fp16 rows (128 B/row).
// Thread t: node b = t>>4, quad q = t&15 (features 4q..4q+3).
__global__ __launch_bounds__(256) void conv_kernel(const float* __restrict__ ue,
                                                   const float* __restrict__ ie,
                                                   half4* __restrict__ xh) {
    int t = blockIdx.x * 256 + threadIdx.x;
    int b = t >> 4;
    int q = t & 15;
    const float4* src = (b < NU_)
        ? ((const float4*)(ue + (size_t)b * D_) + q)
        : ((const float4*)(ie + (size_t)(b - NU_) * D_) + q);
    float4 a = *src;
    half4 h;
    h[0] = (_Float16)a.x; h[1] = (_Float16)a.y;
    h[2] = (_Float16)a.z; h[3] = (_Float16)a.w;
    xh[(size_t)b * 16 + q] = h;
}

// ---------------------------------------------------------------------------
// Two-level exclusive scan (1024 elements per block, Hillis-Steele in LDS).
__global__ __launch_bounds__(1024) void scan_block(const int* __restrict__ in, int n,
                                                   int* __restrict__ out,
                                                   int* __restrict__ psum) {
    __shared__ int lds[1024];
    int g = blockIdx.x * 1024 + threadIdx.x;
    int v = (g < n) ? in[g] : 0;
    lds[threadIdx.x] = v;
    __syncthreads();
    for (int off = 1; off < 1024; off <<= 1) {
        int t = (threadIdx.x >= (unsigned)off) ? lds[threadIdx.x - off] : 0;
        __syncthreads();
        lds[threadIdx.x] += t;
        __syncthreads();
    }
    if (g < n) out[g] = lds[threadIdx.x] - v;     // exclusive
    if (threadIdx.x == 1023 && psum) psum[blockIdx.x] = lds[1023];
}

__global__ __launch_bounds__(256) void scan_add(int* __restrict__ rowptr,
                                                const int* __restrict__ poff) {
    int g = blockIdx.x * 256 + threadIdx.x;
    if (g < NN_) rowptr[g] += poff[g >> 10];
    if (g == 0) rowptr[NN_] = TWO_E;              // total is statically known
}

// ---------------------------------------------------------------------------
// Atomic-free CSR fill: position = rowptr[node] + precomputed rank.
__global__ __launch_bounds__(256) void fill2_kernel(const int* __restrict__ eu,
                                                    const int* __restrict__ ei,
                                                    const int* __restrict__ ru,
                                                    const int* __restrict__ rv,
                                                    const int* __restrict__ rowptr,
                                                    int* __restrict__ adj) {
    int e = blockIdx.x * 256 + threadIdx.x;
    if (e >= E_) return;
    int su = eu[e];
    int sv = ei[e] + NU_;
    adj[rowptr[su] + ru[e]] = sv;
    adj[rowptr[sv] + rv[e]] = su;
}

// ---------------------------------------------------------------------------
// fp16 pull: wave = node v; lane = g*16+q; g = neighbor slot, q = half4 quad.
// Row = 128 B = 16 lanes x 8 B. 4-deep unroll x 4 slots = 16 rows in flight.
// out[v][:] = fp16( inv[v] * sum_n inv[n] * x[n][:] ), accumulation in f32.
__global__ __launch_bounds__(256) void pull_kernel(const half4* __restrict__ xh,
                                                   const float* __restrict__ inv,
                                                   const int* __restrict__ rowptr,
                                                   const int* __restrict__ adj,
                                                   half4* __restrict__ out) {
    int t = blockIdx.x * 256 + threadIdx.x;
    int v = t >> 6;
    int lane = t & 63;
    int g = lane >> 4;        // neighbor slot
    int q = lane & 15;        // feature quad (features 4q..4q+3)
    int beg = rowptr[v];
    int end = rowptr[v + 1];
    float sx = 0.f, sy = 0.f, sz = 0.f, sw = 0.f;
    for (int j = beg; j < end; j += 16) {
#pragma unroll
        for (int u = 0; u < 4; ++u) {
            int i = j + 4 * u + g;
            int n = (i < end) ? adj[i] : 0;
            float w = (i < end) ? inv[n] : 0.0f;
            half4 a = xh[(size_t)n * 16 + q];
            sx += w * (float)a[0];
            sy += w * (float)a[1];
            sz += w * (float)a[2];
            sw += w * (float)a[3];
        }
    }
    // combine the 4 neighbor slots (lanes q, q+16, q+32, q+48)
    sx += __shfl_xor(sx, 16); sy += __shfl_xor(sy, 16);
    sz += __shfl_xor(sz, 16); sw += __shfl_xor(sw, 16);
    sx += __shfl_xor(sx, 32); sy += __shfl_xor(sy, 32);
    sz += __shfl_xor(sz, 32); sw += __shfl_xor(sw, 32);
    if (g == 0) {
        float iv = inv[v];
        half4 o;
        o[0] = (_Float16)(iv * sx); o[1] = (_Float16)(iv * sy);
        o[2] = (_Float16)(iv * sz); o[3] = (_Float16)(iv * sw);
        out[(size_t)v * 16 + q] = o;
    }
}

// ---------------------------------------------------------------------------
// Final layer fused: pull (fp16 x) only the gathered rows, accumulate into Z.
__global__ __launch_bounds__(256) void pullz_kernel(const half4* __restrict__ xh,
                                                    const float* __restrict__ inv,
                                                    const int* __restrict__ rowptr,
                                                    const int* __restrict__ adj,
                                                    const int* __restrict__ users,
                                                    const int* __restrict__ items,
                                                    float* __restrict__ Zu,
                                                    float* __restrict__ Zi) {
    int t = blockIdx.x * 256 + threadIdx.x;
    int b = t >> 6;
    int lane = t & 63;
    int g = lane >> 4;
    int q = lane & 15;
    int node;
    float* Z;
    if (b < B_) { node = users[b];            Z = Zu + (size_t)b * D_; }
    else        { node = items[b - B_] + NU_; Z = Zi + (size_t)(b - B_) * D_; }
    int beg = rowptr[node];
    int end = rowptr[node + 1];
    float sx = 0.f, sy = 0.f, sz = 0.f, sw = 0.f;
    for (int j = beg; j < end; j += 16) {
#pragma unroll
        for (int u = 0; u < 4; ++u) {
            int i = j + 4 * u + g;
            int n = (i < end) ? adj[i] : 0;
            float w = (i < end) ? inv[n] : 0.0f;
            half4 a = xh[(size_t)n * 16 + q];
            sx += w * (float)a[0];
            sy += w * (float)a[1];
            sz += w * (float)a[2];
            sw += w * (float)a[3];
        }
    }
    sx += __shfl_xor(sx, 16); sy += __shfl_xor(sy, 16);
    sz += __shfl_xor(sz, 16); sw += __shfl_xor(sw, 16);
    sx += __shfl_xor(sx, 32); sy += __shfl_xor(sy, 32);
    sz += __shfl_xor(sz, 32); sw += __shfl_xor(sw, 32);
    if (g == 0) {
        float iv = inv[node];
        float4* zp = (float4*)Z + q;
        float4 z = *zp;
        z.x += iv * sx; z.y += iv * sy; z.z += iv * sz; z.w += iv * sw;
        *zp = z;
    }
}

// ---------------------------------------------------------------------------
// Z kernels. zinit reads the ORIGINAL f32 embeddings (layer-0 term exact).
__global__ __launch_bounds__(256) void zinit_kernel(const float* __restrict__ ue,
                                                    const float* __restrict__ ie,
                                                    const int* __restrict__ users,
                                                    const int* __restrict__ items,
                                                    float* __restrict__ Zu,
                                                    float* __restrict__ Zi) {
    int t = blockIdx.x * 256 + threadIdx.x;
    int b = t >> 4;
    int q = t & 15;
    if (b < B_) {
        ((float4*)(Zu + (size_t)b * D_))[q] =
            ((const float4*)(ue + (size_t)users[b] * D_))[q];
    } else {
        int bb = b - B_;
        ((float4*)(Zi + (size_t)bb * D_))[q] =
            ((const float4*)(ie + (size_t)items[bb] * D_))[q];
    }
}

// Accumulate a fp16 layer at the gathered rows into f32 Z.
__global__ __launch_bounds__(256) void zacc_kernel(const half4* __restrict__ xh,
                                                   const int* __restrict__ users,
                                                   const int* __restrict__ items,
                                                   float* __restrict__ Zu,
                                                   float* __restrict__ Zi) {
    int t = blockIdx.x * 256 + threadIdx.x;
    int b = t >> 4;
    int q = t & 15;
    float4* zp;
    size_t node;
    if (b < B_) {
        zp = (float4*)(Zu + (size_t)b * D_) + q;
        node = (size_t)users[b];
    } else {
        int bb = b - B_;
        zp = (float4*)(Zi + (size_t)bb * D_) + q;
        node = (size_t)items[bb] + NU_;
    }
    half4 a = xh[node * 16 + q];
    float4 z = *zp;
    z.x += (float)a[0]; z.y += (float)a[1];
    z.z += (float)a[2]; z.w += (float)a[3];
    *zp = z;
}

// ---------------------------------------------------------------------------
// One wave per pair b. Lane l: f = l>>4, d = l&15.
__global__ __launch_bounds__(256) void score_kernel(const float* __restrict__ Zu,
                                                    const float* __restrict__ Zi,
                                                    const float* __restrict__ fw,
                                                    float* __restrict__ out) {
    int t = blockIdx.x * 256 + threadIdx.x;
    int b = t >> 6;
    int l = t & 63;
    int f = l >> 4;
    int dd = l & 15;
    float pu = Zu[(size_t)b * D_ + l];
    float s = 0.0f;
#pragma unroll
    for (int g = 0; g < 4; ++g) {
        float pi = Zi[(size_t)b * D_ + g * 16 + dd];
        float p = pu * pi;
        p += __shfl_xor(p, 1);
        p += __shfl_xor(p, 2);
        p += __shfl_xor(p, 4);
        p += __shfl_xor(p, 8);
        s += fw[f * 4 + g] * p;
    }
    s += __shfl_xor(s, 16);
    s += __shfl_xor(s, 32);
    if (l == 0) out[b] = s * 0.0625f;  // (1/4)*(1/4) layer-mean scaling
}

// ---------------------------------------------------------------------------
extern "C" void kernel_launch(void* const* d_in, const int* in_sizes, int n_in,
                              void* d_out, int out_size, void* d_ws, size_t ws_size,
                              hipStream_t stream) {
    const float* ue    = (const float*)d_in[0];  // [NU, 64]
    const float* ie    = (const float*)d_in[1];  // [NI, 64]
    const float* fw    = (const float*)d_in[2];  // [4, 4]
    const int*   eu    = (const int*)d_in[3];    // [E]
    const int*   eitem = (const int*)d_in[4];    // [E]
    const int*   users = (const int*)d_in[5];    // [B]
    const int*   items = (const int*)d_in[6];    // [B]
    float* scores = (float*)d_out;               // [B]

    const size_t xh_bytes = (size_t)NN_ * D_ * 2;             // 89.6 MB (fp16)
    const size_t zbytes   = (size_t)B_ * D_ * sizeof(float);  // 33.55 MB
    const int NB_SCAN = (NN_ + 1023) / 1024;                  // 684

    char* ws = (char*)d_ws;
    half4* X0h   = (half4*)ws;  ws += xh_bytes;
    half4* XAh   = (half4*)ws;  ws += xh_bytes;
    half4* XBh   = (half4*)ws;  ws += xh_bytes;
    float* Zu    = (float*)ws;  ws += zbytes;
    float* Zi    = (float*)ws;  ws += zbytes;
    float* inv   = (float*)ws;  ws += (size_t)NN_ * 4;
    int*   deg   = (int*)ws;    ws += (size_t)NN_ * 4;
    int*   rowptr= (int*)ws;    ws += (size_t)(NN_ + 1) * 4;
    int*   adj   = (int*)ws;    ws += (size_t)TWO_E * 4;      // 16 MB
    int*   psum  = (int*)ws;    ws += (size_t)NB_SCAN * 4;
    int*   poff  = (int*)ws;    ws += (size_t)NB_SCAN * 4;

    // Aliases (lifetimes disjoint, stream-ordered):
    //  - padded counters degp (NN*32*4 = 89.6 MB) live in XAh; dead after
    //    compact_inv, before layer-1 pull writes XAh.
    //  - rank arrays ru/rv (16 MB) live in XBh; dead after fill2, before
    //    layer-2 pull writes XBh.
    int* degp = (int*)XAh;
    int* ru   = (int*)XBh;
    int* rv   = (int*)XBh + E_;

    // --- CSR build (rank-from-degree, atomic-free fill) ----------------
    hipMemsetAsync(degp, 0, (size_t)NN_ * PAD_ * 4, stream);
    deg_rank_kernel<<<(E_ + 255) / 256, 256, 0, stream>>>(eu, eitem, degp, ru, rv);
    compact_inv_kernel<<<(NN_ + 255) / 256, 256, 0, stream>>>(degp, deg, inv);
    scan_block<<<NB_SCAN, 1024, 0, stream>>>(deg, NN_, rowptr, psum);
    scan_block<<<1, 1024, 0, stream>>>(psum, NB_SCAN, poff, (int*)nullptr);
    scan_add<<<(NN_ + 255) / 256, 256, 0, stream>>>(rowptr, poff);
    fill2_kernel<<<(E_ + 255) / 256, 256, 0, stream>>>(eu, eitem, ru, rv, rowptr, adj);

    // --- fp16 conversion of layer-0 X ----------------------------------
    conv_kernel<<<(NN_ * 16) / 256, 256, 0, stream>>>(ue, ie, X0h);

    // --- Z init at layer-0 embeddings (exact f32) ----------------------
    zinit_kernel<<<(2 * B_ * 16) / 256, 256, 0, stream>>>(ue, ie, users, items, Zu, Zi);

    // --- 3 propagation layers (fp16 pull) ------------------------------
    pull_kernel<<<(NN_ * D_) / 256, 256, 0, stream>>>(X0h, inv, rowptr, adj, XAh);
    zacc_kernel<<<(2 * B_ * 16) / 256, 256, 0, stream>>>(XAh, users, items, Zu, Zi);
    pull_kernel<<<(NN_ * D_) / 256, 256, 0, stream>>>(XAh, inv, rowptr, adj, XBh);
    zacc_kernel<<<(2 * B_ * 16) / 256, 256, 0, stream>>>(XBh, users, items, Zu, Zi);
    // Layer 3: only the gathered rows are needed — fuse into Z.
    pullz_kernel<<<(2 * B_ * D_) / 256, 256, 0, stream>>>(
        XBh, inv, rowptr, adj, users, items, Zu, Zi);

    // --- scores --------------------------------------------------------
    score_kernel<<<(B_ * D_) / 256, 256, 0, stream>>>(Zu, Zi, fw, scores);
}

// Round 6
// 1050.614 us; speedup vs baseline: 2.7970x; 1.0140x over previous
//
#include <hip/hip_runtime.h>
#include <math.h>

// Problem constants (match reference)
#define NU_ 500000
#define NI_ 200000
#define NN_ 700000            // NU + NI
#define D_  64
#define E_  2000000
#define B_  131072
#define TWO_E 4000000

typedef _Float16 half4 __attribute__((ext_vector_type(4)));  // 8 B
typedef _Float16 half8 __attribute__((ext_vector_type(8)));  // 16 B

// ---------------------------------------------------------------------------
// Degree histogram + rank assignment in one pass. Device-scope atomics are
// resolved memory-side, so no line padding (2.8 MB array, cheap memset).
__global__ __launch_bounds__(256) void deg_rank_kernel(const int* __restrict__ eu,
                                                       const int* __restrict__ ei,
                                                       int* __restrict__ deg,
                                                       int* __restrict__ ru,
                                                       int* __restrict__ rv) {
    int e = blockIdx.x * 256 + threadIdx.x;
    if (e >= E_) return;
    int su = eu[e];
    int sv = ei[e] + NU_;
    ru[e] = atomicAdd(&deg[su], 1);
    rv[e] = atomicAdd(&deg[sv], 1);
}

__global__ __launch_bounds__(256) void inv_kernel(const int* __restrict__ deg,
                                                  float* __restrict__ inv) {
    int v = blockIdx.x * 256 + threadIdx.x;
    if (v >= NN_) return;
    int d = deg[v];
    inv[v] = (d > 0) ? (1.0f / sqrtf((float)d)) : 0.0f;
}

// ---------------------------------------------------------------------------
// Convert the concatenated [ue; ie] f32 embeddings to fp16 rows (128 B/row).
__global__ __launch_bounds__(256) void conv_kernel(const float* __restrict__ ue,
                                                   const float* __restrict__ ie,
                                                   half4* __restrict__ xh) {
    int t = blockIdx.x * 256 + threadIdx.x;
    int b = t >> 4;
    int q = t & 15;
    const float4* src = (b < NU_)
        ? ((const float4*)(ue + (size_t)b * D_) + q)
        : ((const float4*)(ie + (size_t)(b - NU_) * D_) + q);
    float4 a = *src;
    half4 h;
    h[0] = (_Float16)a.x; h[1] = (_Float16)a.y;
    h[2] = (_Float16)a.z; h[3] = (_Float16)a.w;
    xh[(size_t)b * 16 + q] = h;
}

// ---------------------------------------------------------------------------
// Two-level exclusive scan (1024 elements per block, Hillis-Steele in LDS).
__global__ __launch_bounds__(1024) void scan_block(const int* __restrict__ in, int n,
                                                   int* __restrict__ out,
                                                   int* __restrict__ psum) {
    __shared__ int lds[1024];
    int g = blockIdx.x * 1024 + threadIdx.x;
    int v = (g < n) ? in[g] : 0;
    lds[threadIdx.x] = v;
    __syncthreads();
    for (int off = 1; off < 1024; off <<= 1) {
        int t = (threadIdx.x >= (unsigned)off) ? lds[threadIdx.x - off] : 0;
        __syncthreads();
        lds[threadIdx.x] += t;
        __syncthreads();
    }
    if (g < n) out[g] = lds[threadIdx.x] - v;     // exclusive
    if (threadIdx.x == 1023 && psum) psum[blockIdx.x] = lds[1023];
}

__global__ __launch_bounds__(256) void scan_add(int* __restrict__ rowptr,
                                                const int* __restrict__ poff) {
    int g = blockIdx.x * 256 + threadIdx.x;
    if (g < NN_) rowptr[g] += poff[g >> 10];
    if (g == 0) rowptr[NN_] = TWO_E;              // total is statically known
}

// ---------------------------------------------------------------------------
// Atomic-free CSR fill with fused weights: adjw[pos] = {nbr, inv[nbr]}.
__global__ __launch_bounds__(256) void fill2_kernel(const int* __restrict__ eu,
                                                    const int* __restrict__ ei,
                                                    const int* __restrict__ ru,
                                                    const int* __restrict__ rv,
                                                    const int* __restrict__ rowptr,
                                                    const float* __restrict__ inv,
                                                    int2* __restrict__ adjw) {
    int e = blockIdx.x * 256 + threadIdx.x;
    if (e >= E_) return;
    int su = eu[e];
    int sv = ei[e] + NU_;
    float wu = inv[su];
    float wv = inv[sv];
    adjw[rowptr[su] + ru[e]] = make_int2(sv, __float_as_int(wv));
    adjw[rowptr[sv] + rv[e]] = make_int2(su, __float_as_int(wu));
}

// ---------------------------------------------------------------------------
// fp16 pull, 8-slot layout: lane = g*8+q; g = neighbor slot (8), q = feature
// octet (8 fp16 = 16 B). One row = 8 lanes x 16 B. 4-deep u-loop -> up to 32
// rows in flight per wave; wave-uniform early-skip for short rows.
// out[v][:] = fp16( inv[v] * sum_n w_n * x[n][:] ), accumulation in f32.
__global__ __launch_bounds__(256) void pull_kernel(const half8* __restrict__ xh,
                                                   const float* __restrict__ inv,
                                                   const int* __restrict__ rowptr,
                                                   const int2* __restrict__ adjw,
                                                   half8* __restrict__ out) {
    int t = blockIdx.x * 256 + threadIdx.x;
    int v = t >> 6;
    int lane = t & 63;
    int g = lane >> 3;        // neighbor slot (0..7)
    int q = lane & 7;         // feature octet (features 8q..8q+7)
    int beg = rowptr[v];
    int end = rowptr[v + 1];
    float acc[8] = {0.f, 0.f, 0.f, 0.f, 0.f, 0.f, 0.f, 0.f};
    for (int j = beg; j < end; j += 32) {
#pragma unroll
        for (int u = 0; u < 4; ++u) {
            int base = j + 8 * u;
            if (base < end) {                      // wave-uniform skip
                int i = base + g;
                int2 aw = (i < end) ? adjw[i] : make_int2(0, 0);
                float w = __int_as_float(aw.y);    // 0.0f for masked slots
                half8 a = xh[(size_t)aw.x * 8 + q];
#pragma unroll
                for (int k = 0; k < 8; ++k)
                    acc[k] += w * (float)a[k];
            }
        }
    }
    // combine the 8 neighbor slots (g occupies lane bits 3..5)
#pragma unroll
    for (int k = 0; k < 8; ++k) {
        acc[k] += __shfl_xor(acc[k], 8);
        acc[k] += __shfl_xor(acc[k], 16);
        acc[k] += __shfl_xor(acc[k], 32);
    }
    if (g == 0) {
        float iv = inv[v];
        half8 o;
#pragma unroll
        for (int k = 0; k < 8; ++k) o[k] = (_Float16)(iv * acc[k]);
        out[(size_t)v * 8 + q] = o;
    }
}

// ---------------------------------------------------------------------------
// Final layer fused: pull only the gathered rows, accumulate into f32 Z.
__global__ __launch_bounds__(256) void pullz_kernel(const half8* __restrict__ xh,
                                                    const float* __restrict__ inv,
                                                    const int* __restrict__ rowptr,
                                                    const int2* __restrict__ adjw,
                                                    const int* __restrict__ users,
                                                    const int* __restrict__ items,
                                                    float* __restrict__ Zu,
                                                    float* __restrict__ Zi) {
    int t = blockIdx.x * 256 + threadIdx.x;
    int b = t >> 6;
    int lane = t & 63;
    int g = lane >> 3;
    int q = lane & 7;
    int node;
    float* Z;
    if (b < B_) { node = users[b];            Z = Zu + (size_t)b * D_; }
    else        { node = items[b - B_] + NU_; Z = Zi + (size_t)(b - B_) * D_; }
    int beg = rowptr[node];
    int end = rowptr[node + 1];
    float acc[8] = {0.f, 0.f, 0.f, 0.f, 0.f, 0.f, 0.f, 0.f};
    for (int j = beg; j < end; j += 32) {
#pragma unroll
        for (int u = 0; u < 4; ++u) {
            int base = j + 8 * u;
            if (base < end) {
                int i = base + g;
                int2 aw = (i < end) ? adjw[i] : make_int2(0, 0);
                float w = __int_as_float(aw.y);
                half8 a = xh[(size_t)aw.x * 8 + q];
#pragma unroll
                for (int k = 0; k < 8; ++k)
                    acc[k] += w * (float)a[k];
            }
        }
    }
#pragma unroll
    for (int k = 0; k < 8; ++k) {
        acc[k] += __shfl_xor(acc[k], 8);
        acc[k] += __shfl_xor(acc[k], 16);
        acc[k] += __shfl_xor(acc[k], 32);
    }
    if (g == 0) {
        float iv = inv[node];
        float4* zp = (float4*)Z + 2 * q;          // features 8q..8q+7
        float4 z0 = zp[0], z1 = zp[1];
        z0.x += iv * acc[0]; z0.y += iv * acc[1];
        z0.z += iv * acc[2]; z0.w += iv * acc[3];
        z1.x += iv * acc[4]; z1.y += iv * acc[5];
        z1.z += iv * acc[6]; z1.w += iv * acc[7];
        zp[0] = z0; zp[1] = z1;
    }
}

// ---------------------------------------------------------------------------
// Z kernels. zinit reads the ORIGINAL f32 embeddings (layer-0 term exact).
__global__ __launch_bounds__(256) void zinit_kernel(const float* __restrict__ ue,
                                                    const float* __restrict__ ie,
                                                    const int* __restrict__ users,
                                                    const int* __restrict__ items,
                                                    float* __restrict__ Zu,
                                                    float* __restrict__ Zi) {
    int t = blockIdx.x * 256 + threadIdx.x;
    int b = t >> 4;
    int q = t & 15;
    if (b < B_) {
        ((float4*)(Zu + (size_t)b * D_))[q] =
            ((const float4*)(ue + (size_t)users[b] * D_))[q];
    } else {
        int bb = b - B_;
        ((float4*)(Zi + (size_t)bb * D_))[q] =
            ((const float4*)(ie + (size_t)items[bb] * D_))[q];
    }
}

// Accumulate a fp16 layer at the gathered rows into f32 Z.
__global__ __launch_bounds__(256) void zacc_kernel(const half4* __restrict__ xh,
                                                   const int* __restrict__ users,
                                                   const int* __restrict__ items,
                                                   float* __restrict__ Zu,
                                                   float* __restrict__ Zi) {
    int t = blockIdx.x * 256 + threadIdx.x;
    int b = t >> 4;
    int q = t & 15;
    float4* zp;
    size_t node;
    if (b < B_) {
        zp = (float4*)(Zu + (size_t)b * D_) + q;
        node = (size_t)users[b];
    } else {
        int bb = b - B_;
        zp = (float4*)(Zi + (size_t)bb * D_) + q;
        node = (size_t)items[bb] + NU_;
    }
    half4 a = xh[node * 16 + q];
    float4 z = *zp;
    z.x += (float)a[0]; z.y += (float)a[1];
    z.z += (float)a[2]; z.w += (float)a[3];
    *zp = z;
}

// ---------------------------------------------------------------------------
// One wave per pair b. Lane l: f = l>>4, d = l&15.
__global__ __launch_bounds__(256) void score_kernel(const float* __restrict__ Zu,
                                                    const float* __restrict__ Zi,
                                                    const float* __restrict__ fw,
                                                    float* __restrict__ out) {
    int t = blockIdx.x * 256 + threadIdx.x;
    int b = t >> 6;
    int l = t & 63;
    int f = l >> 4;
    int dd = l & 15;
    float pu = Zu[(size_t)b * D_ + l];
    float s = 0.0f;
#pragma unroll
    for (int g = 0; g < 4; ++g) {
        float pi = Zi[(size_t)b * D_ + g * 16 + dd];
        float p = pu * pi;
        p += __shfl_xor(p, 1);
        p += __shfl_xor(p, 2);
        p += __shfl_xor(p, 4);
        p += __shfl_xor(p, 8);
        s += fw[f * 4 + g] * p;
    }
    s += __shfl_xor(s, 16);
    s += __shfl_xor(s, 32);
    if (l == 0) out[b] = s * 0.0625f;  // (1/4)*(1/4) layer-mean scaling
}

// ---------------------------------------------------------------------------
extern "C" void kernel_launch(void* const* d_in, const int* in_sizes, int n_in,
                              void* d_out, int out_size, void* d_ws, size_t ws_size,
                              hipStream_t stream) {
    const float* ue    = (const float*)d_in[0];  // [NU, 64]
    const float* ie    = (const float*)d_in[1];  // [NI, 64]
    const float* fw    = (const float*)d_in[2];  // [4, 4]
    const int*   eu    = (const int*)d_in[3];    // [E]
    const int*   eitem = (const int*)d_in[4];    // [E]
    const int*   users = (const int*)d_in[5];    // [B]
    const int*   items = (const int*)d_in[6];    // [B]
    float* scores = (float*)d_out;               // [B]

    const size_t xh_bytes = (size_t)NN_ * D_ * 2;             // 89.6 MB (fp16)
    const size_t zbytes   = (size_t)B_ * D_ * sizeof(float);  // 33.55 MB
    const int NB_SCAN = (NN_ + 1023) / 1024;                  // 684

    char* ws = (char*)d_ws;
    half8* X0h   = (half8*)ws;  ws += xh_bytes;
    half8* XAh   = (half8*)ws;  ws += xh_bytes;
    half8* XBh   = (half8*)ws;  ws += xh_bytes;
    float* Zu    = (float*)ws;  ws += zbytes;
    float* Zi    = (float*)ws;  ws += zbytes;
    float* inv   = (float*)ws;  ws += (size_t)NN_ * 4;
    int*   deg   = (int*)ws;    ws += (size_t)NN_ * 4;
    int*   rowptr= (int*)ws;    ws += (size_t)(NN_ + 1) * 4;
    int2*  adjw  = (int2*)ws;   ws += (size_t)TWO_E * 8;      // 32 MB
    int*   psum  = (int*)ws;    ws += (size_t)NB_SCAN * 4;
    int*   poff  = (int*)ws;    ws += (size_t)NB_SCAN * 4;

    // Rank arrays ru/rv (16 MB) alias XBh: dead after fill2, which runs
    // before the layer-2 pull writes XBh (stream-ordered).
    int* ru = (int*)XBh;
    int* rv = (int*)XBh + E_;

    // --- CSR build (rank-from-degree, atomic-free weighted fill) -------
    hipMemsetAsync(deg, 0, (size_t)NN_ * 4, stream);
    deg_rank_kernel<<<(E_ + 255) / 256, 256, 0, stream>>>(eu, eitem, deg, ru, rv);
    inv_kernel<<<(NN_ + 255) / 256, 256, 0, stream>>>(deg, inv);
    scan_block<<<NB_SCAN, 1024, 0, stream>>>(deg, NN_, rowptr, psum);
    scan_block<<<1, 1024, 0, stream>>>(psum, NB_SCAN, poff, (int*)nullptr);
    scan_add<<<(NN_ + 255) / 256, 256, 0, stream>>>(rowptr, poff);
    fill2_kernel<<<(E_ + 255) / 256, 256, 0, stream>>>(eu, eitem, ru, rv, rowptr, inv, adjw);

    // --- fp16 conversion of layer-0 X ----------------------------------
    conv_kernel<<<(NN_ * 16) / 256, 256, 0, stream>>>(ue, ie, (half4*)X0h);

    // --- Z init at layer-0 embeddings (exact f32) ----------------------
    zinit_kernel<<<(2 * B_ * 16) / 256, 256, 0, stream>>>(ue, ie, users, items, Zu, Zi);

    // --- 3 propagation layers (fp16 pull) ------------------------------
    pull_kernel<<<(NN_ * D_) / 256, 256, 0, stream>>>(X0h, inv, rowptr, adjw, XAh);
    zacc_kernel<<<(2 * B_ * 16) / 256, 256, 0, stream>>>((const half4*)XAh, users, items, Zu, Zi);
    pull_kernel<<<(NN_ * D_) / 256, 256, 0, stream>>>(XAh, inv, rowptr, adjw, XBh);
    zacc_kernel<<<(2 * B_ * 16) / 256, 256, 0, stream>>>((const half4*)XBh, users, items, Zu, Zi);
    // Layer 3: only the gathered rows are needed — fuse into Z.
    pullz_kernel<<<(2 * B_ * D_) / 256, 256, 0, stream>>>(
        XBh, inv, rowptr, adjw, users, items, Zu, Zi);

    // --- scores --------------------------------------------------------
    score_kernel<<<(B_ * D_) / 256, 256, 0, stream>>>(Zu, Zi, fw, scores);
}